// Round 8
// baseline (237.237 us; speedup 1.0000x reference)
//
#include <hip/hip_runtime.h>
#include <math.h>

// GATv2 x2 layers, N=50000, E=600000, D=128.
//  CSR over dst (memset + atomic count + hierarchical scan + scatter) ->
//  per layer: register-resident-W MFMA GEMM (XL bf16, XR bf16, RES fp32),
//  then per-node aggregation: 1 wave/node, 4 edge-groups of 16 lanes,
//  8 dims/lane (uint4 gathers), 4-stage reduce, exp2 with prescaled att,
//  no-max-sub softmax (validated r6/r7), 2-stage cross-group merge,
//  1-batch software pipeline on the gather chain.

#define DIM 128
#define NEG_SLOPE 0.2f
#define TPW 4

typedef __attribute__((ext_vector_type(8))) short short8;
typedef __attribute__((ext_vector_type(4))) float floatx4;
typedef __attribute__((ext_vector_type(2))) float f32x2;

static __device__ __forceinline__ unsigned short f2b(float f) {
    unsigned u = __float_as_uint(f);
    unsigned r = (u + 0x7FFFu + ((u >> 16) & 1u)) >> 16;   // RNE
    return (unsigned short)r;
}
// one u32 holding two bf16 (lo = dim d, hi = dim d+1) -> f32 pair
static __device__ __forceinline__ f32x2 cvt2(unsigned u) {
    f32x2 r;
    r.x = __uint_as_float(u << 16);
    r.y = __uint_as_float(u & 0xffff0000u);
    return r;
}
static __device__ __forceinline__ f32x2 pk_add(f32x2 a, f32x2 b) {
    f32x2 d;
    asm("v_pk_add_f32 %0, %1, %2" : "=v"(d) : "v"(a), "v"(b));
    return d;
}
static __device__ __forceinline__ f32x2 pk_mul(f32x2 a, f32x2 b) {
    f32x2 d;
    asm("v_pk_mul_f32 %0, %1, %2" : "=v"(d) : "v"(a), "v"(b));
    return d;
}
static __device__ __forceinline__ f32x2 pk_fma(f32x2 a, f32x2 b, f32x2 c) {
    f32x2 d;
    asm("v_pk_fma_f32 %0, %1, %2, %3" : "=v"(d) : "v"(a), "v"(b), "v"(c));
    return d;
}
static __device__ __forceinline__ f32x2 absf2(f32x2 a) {
    f32x2 r;
    r.x = __builtin_fabsf(a.x);
    r.y = __builtin_fabsf(a.y);
    return r;
}

// ---------------- CSR build ----------------
__global__ void k_count(const int* __restrict__ dst, int E, int* __restrict__ counts) {
    int k = blockIdx.x * blockDim.x + threadIdx.x;
    if (k < E) atomicAdd(&counts[dst[k]], 1);
}

__global__ void k_scan1(const int* __restrict__ counts, int n,
                        int* __restrict__ rowptr, int* __restrict__ bsum) {
    __shared__ int s[256];
    int tid = threadIdx.x;
    int i = blockIdx.x * 256 + tid;
    int v = (i < n) ? (counts[i] + 1) : 0;   // +1 self loop
    s[tid] = v;
    __syncthreads();
    for (int off = 1; off < 256; off <<= 1) {
        int t = (tid >= off) ? s[tid - off] : 0;
        __syncthreads();
        s[tid] += t;
        __syncthreads();
    }
    if (i < n) rowptr[i + 1] = s[tid];
    if (tid == 255) bsum[blockIdx.x] = s[255];
}

__global__ void k_scan2(int* __restrict__ bsum, int nb) {
    __shared__ int s[256];
    int tid = threadIdx.x;
    int v = (tid < nb) ? bsum[tid] : 0;
    s[tid] = v;
    __syncthreads();
    for (int off = 1; off < 256; off <<= 1) {
        int t = (tid >= off) ? s[tid - off] : 0;
        __syncthreads();
        s[tid] += t;
        __syncthreads();
    }
    if (tid < nb) bsum[tid] = s[tid];
}

__global__ void k_scan3(int* __restrict__ rowptr, const int* __restrict__ bsum,
                        int n, int* __restrict__ counts_to_cursors) {
    int i = blockIdx.x * 256 + threadIdx.x;
    if (i < n) {
        int add = (blockIdx.x > 0) ? bsum[blockIdx.x - 1] : 0;
        int cnt = counts_to_cursors[i] + 1;
        int v = rowptr[i + 1] + add;
        rowptr[i + 1] = v;
        counts_to_cursors[i] = v - cnt;  // cursor = exclusive prefix
    }
    if (i == 0) rowptr[0] = 0;
}

__global__ void k_scatter(const int* __restrict__ src, const int* __restrict__ dst,
                          int E, int n, int* __restrict__ cur, int* __restrict__ srt) {
    int k = blockIdx.x * blockDim.x + threadIdx.x;
    int tot = E + n;
    if (k >= tot) return;
    int s, d;
    if (k < E) { s = src[k]; d = dst[k]; }
    else       { s = k - E;  d = s; }
    int p = atomicAdd(&cur[d], 1);
    srt[p] = s;
}

// ---------------- fused pre-pass: W fragmentization + H fragmentization ----------------
__global__ void k_pre(const float* __restrict__ Wl, const float* __restrict__ Wr,
                      const float* __restrict__ Wres, unsigned short* __restrict__ wfrag,
                      const float* __restrict__ h, unsigned short* __restrict__ hfrag,
                      int n, int ntiles) {
    int blk = blockIdx.x;
    if (blk < 48) {
        int idx = blk * 256 + threadIdx.x;      // < 2*3*4*8*64 = 12288
        int lane = idx & 63;
        int nr   = (idx >> 6) & 7;
        int ks   = (idx >> 9) & 3;
        int v    = idx >> 11;                   // l*3+sec
        int sec = v % 3, l = v / 3;
        const float* W = (sec == 0) ? (Wl + l * DIM * DIM)
                       : (sec == 1) ? (Wr + l * DIM * DIM) : Wres;
        int nn = nr * 16 + (lane & 15);
        int k0 = ks * 32 + ((lane >> 4) << 3);
        ushort4 a, b;
        a.x = f2b(W[(k0 + 0) * DIM + nn]); a.y = f2b(W[(k0 + 1) * DIM + nn]);
        a.z = f2b(W[(k0 + 2) * DIM + nn]); a.w = f2b(W[(k0 + 3) * DIM + nn]);
        b.x = f2b(W[(k0 + 4) * DIM + nn]); b.y = f2b(W[(k0 + 5) * DIM + nn]);
        b.z = f2b(W[(k0 + 6) * DIM + nn]); b.w = f2b(W[(k0 + 7) * DIM + nn]);
        *(ushort4*)(wfrag + (size_t)idx * 8) = a;
        *(ushort4*)(wfrag + (size_t)idx * 8 + 4) = b;
    } else {
        int idx = (blk - 48) * 256 + threadIdx.x;
        if (idx >= ntiles * 256) return;
        int lane = idx & 63;
        int ks   = (idx >> 6) & 3;
        int tile = idx >> 8;
        int row  = tile * 16 + (lane & 15);
        int col0 = ks * 32 + ((lane >> 4) << 3);
        ushort4 a = {0, 0, 0, 0}, b = {0, 0, 0, 0};
        if (row < n) {
            float4 v0 = *(const float4*)(h + (size_t)row * DIM + col0);
            float4 v1 = *(const float4*)(h + (size_t)row * DIM + col0 + 4);
            a.x = f2b(v0.x); a.y = f2b(v0.y); a.z = f2b(v0.z); a.w = f2b(v0.w);
            b.x = f2b(v1.x); b.y = f2b(v1.y); b.z = f2b(v1.z); b.w = f2b(v1.w);
        }
        *(ushort4*)(hfrag + (size_t)idx * 8) = a;
        *(ushort4*)(hfrag + (size_t)idx * 8 + 4) = b;
    }
}

// ---------------- register-resident-W MFMA GEMM ----------------
__global__ __launch_bounds__(256, 2) void k_gemm(
    const unsigned short* __restrict__ hfrag, const unsigned short* __restrict__ wfrag,
    const float* __restrict__ bl, const float* __restrict__ br, const float* __restrict__ bres,
    unsigned short* __restrict__ XLb, unsigned short* __restrict__ XRb,
    float* __restrict__ RES, int ntiles)
{
    int sec  = blockIdx.y;
    int lane = threadIdx.x & 63;
    int w    = threadIdx.x >> 6;

    const unsigned short* wbase = wfrag + (size_t)sec * (4 * 8 * 64 * 8);
    short8 bf[4][8];
#pragma unroll
    for (int ks = 0; ks < 4; ks++)
#pragma unroll
        for (int nr = 0; nr < 8; nr++)
            bf[ks][nr] = *(const short8*)(wbase + (((ks * 8 + nr) * 64 + lane) << 3));

    const float* bias = (sec == 0) ? bl : (sec == 1) ? br : bres;
    int colb = (lane >> 4) << 2;
    float4 bv[8];
#pragma unroll
    for (int nr = 0; nr < 8; nr++) bv[nr] = *(const float4*)(bias + nr * 16 + colb);

    int wid = blockIdx.x * 4 + w;
#pragma unroll
    for (int i = 0; i < TPW; i++) {
        int t = wid * TPW + i;
        if (t >= ntiles) break;
        short8 a[4];
#pragma unroll
        for (int ks = 0; ks < 4; ks++)
            a[ks] = *(const short8*)(hfrag + (((t * 4 + ks) * 64 + lane) << 3));
        floatx4 acc[8];
#pragma unroll
        for (int nr = 0; nr < 8; nr++) acc[nr] = (floatx4){0.f, 0.f, 0.f, 0.f};
#pragma unroll
        for (int ks = 0; ks < 4; ks++)
#pragma unroll
            for (int nr = 0; nr < 8; nr++)
                acc[nr] = __builtin_amdgcn_mfma_f32_16x16x32_bf16(bf[ks][nr], a[ks], acc[nr], 0, 0, 0);

        int row = t * 16 + (lane & 15);
        size_t rb = (size_t)row * DIM;
#pragma unroll
        for (int nr = 0; nr < 8; nr++) {
            float4 o;
            o.x = acc[nr][0] + bv[nr].x;
            o.y = acc[nr][1] + bv[nr].y;
            o.z = acc[nr][2] + bv[nr].z;
            o.w = acc[nr][3] + bv[nr].w;
            int col = nr * 16 + colb;
            if (sec == 2) {
                *(float4*)(RES + rb + col) = o;
            } else {
                ushort4 u;
                u.x = f2b(o.x); u.y = f2b(o.y); u.z = f2b(o.z); u.w = f2b(o.w);
                if (sec == 0) *(ushort4*)(XLb + rb + col) = u;
                else          *(ushort4*)(XRb + rb + col) = u;
            }
        }
    }
}

// ---------------- aggregation: 4 groups x 16 lanes, 8 dims/lane ----------------
__global__ __launch_bounds__(256) void k_aggr(
    const unsigned short* __restrict__ XLb, const unsigned short* __restrict__ XRb,
    const float* __restrict__ RES, const float* __restrict__ att,
    const float* __restrict__ bias, const int* __restrict__ rowptr,
    const int* __restrict__ srt, float* __restrict__ outF,
    unsigned short* __restrict__ fragOut, int writeFrag, int n)
{
    int wave = threadIdx.x >> 6;
    int lane = threadIdx.x & 63;
    int node = blockIdx.x * 4 + wave;
    if (node >= n) return;
    int g = lane >> 4;        // edge slot 0..3
    int i = lane & 15;        // dim slice [8i, 8i+8)
    int d0 = i << 3;

    const float S6 = 0.6f * 1.44269504089f;   // fold log2(e) into att
    const float S4 = 0.4f * 1.44269504089f;
    float4 af0 = *(const float4*)(att + d0);
    float4 af1 = *(const float4*)(att + d0 + 4);
    f32x2 a6[4] = {{S6 * af0.x, S6 * af0.y}, {S6 * af0.z, S6 * af0.w},
                   {S6 * af1.x, S6 * af1.y}, {S6 * af1.z, S6 * af1.w}};
    f32x2 a4[4] = {{S4 * af0.x, S4 * af0.y}, {S4 * af0.z, S4 * af0.w},
                   {S4 * af1.x, S4 * af1.y}, {S4 * af1.z, S4 * af1.w}};

    uint4 xu = *(const uint4*)(XRb + (size_t)node * DIM + d0);
    f32x2 xv0 = cvt2(xu.x), xv1 = cvt2(xu.y), xv2 = cvt2(xu.z), xv3 = cvt2(xu.w);

    int beg = rowptr[node], end = rowptr[node + 1];
    const uint4* R = (const uint4*)XLb;   // row s, slice i at R[s*16 + i]

    f32x2 acc0 = {0.f, 0.f}, acc1 = {0.f, 0.f}, acc2 = {0.f, 0.f}, acc3 = {0.f, 0.f};
    float den = 0.f;

    // software pipeline: prefetch batch jb, compute while prefetching jb+4
    int jj = beg + g;
    int s0 = srt[(jj < end) ? jj : (end - 1)];
    uint4 u = R[((size_t)s0 << 4) + i];

    for (int jb = beg; jb < end; jb += 4) {
        int jjn = jb + 4 + g;
        int sn = srt[(jjn < end) ? jjn : (end - 1)];
        uint4 un = R[((size_t)sn << 4) + i];

        f32x2 v0 = cvt2(u.x), v1 = cvt2(u.y), v2 = cvt2(u.z), v3 = cvt2(u.w);
        f32x2 t0 = pk_add(v0, xv0);
        f32x2 t1 = pk_add(v1, xv1);
        f32x2 t2 = pk_add(v2, xv2);
        f32x2 t3 = pk_add(v3, xv3);
        f32x2 pp = pk_mul(a6[0], t0);
        pp = pk_fma(a6[1], t1, pp);
        pp = pk_fma(a6[2], t2, pp);
        pp = pk_fma(a6[3], t3, pp);
        pp = pk_fma(a4[0], absf2(t0), pp);
        pp = pk_fma(a4[1], absf2(t1), pp);
        pp = pk_fma(a4[2], absf2(t2), pp);
        pp = pk_fma(a4[3], absf2(t3), pp);
        float p = pp.x + pp.y;
        p += __shfl_xor(p, 1);
        p += __shfl_xor(p, 2);
        p += __shfl_xor(p, 4);
        p += __shfl_xor(p, 8);
        float w = __builtin_exp2f(fminf(p, 120.f));   // e^logit (log2e folded)
        w = (jb + g < end) ? w : 0.f;
        den += w;
        f32x2 wp = {w, w};
        acc0 = pk_fma(wp, v0, acc0);
        acc1 = pk_fma(wp, v1, acc1);
        acc2 = pk_fma(wp, v2, acc2);
        acc3 = pk_fma(wp, v3, acc3);

        u = un;
        jj = jjn;
    }

    // merge the 4 groups (pure sums)
#pragma unroll
    for (int off = 16; off <= 32; off <<= 1) {
        den    += __shfl_xor(den, off);
        acc0.x += __shfl_xor(acc0.x, off);
        acc0.y += __shfl_xor(acc0.y, off);
        acc1.x += __shfl_xor(acc1.x, off);
        acc1.y += __shfl_xor(acc1.y, off);
        acc2.x += __shfl_xor(acc2.x, off);
        acc2.y += __shfl_xor(acc2.y, off);
        acc3.x += __shfl_xor(acc3.x, off);
        acc3.y += __shfl_xor(acc3.y, off);
    }
    if (g) return;

    // epilogue on lanes 0..15, each owns dims [8i, 8i+8)
    float inv = 1.f / (den + 1e-16f);
    float4 r0 = *(const float4*)(RES + (size_t)node * DIM + d0);
    float4 r1 = *(const float4*)(RES + (size_t)node * DIM + d0 + 4);
    float4 b0 = *(const float4*)(bias + d0);
    float4 b1 = *(const float4*)(bias + d0 + 4);
    float of[8];
    of[0] = fmaxf(acc0.x * inv + b0.x + r0.x, 0.f);
    of[1] = fmaxf(acc0.y * inv + b0.y + r0.y, 0.f);
    of[2] = fmaxf(acc1.x * inv + b0.z + r0.z, 0.f);
    of[3] = fmaxf(acc1.y * inv + b0.w + r0.w, 0.f);
    of[4] = fmaxf(acc2.x * inv + b1.x + r1.x, 0.f);
    of[5] = fmaxf(acc2.y * inv + b1.y + r1.y, 0.f);
    of[6] = fmaxf(acc3.x * inv + b1.z + r1.z, 0.f);
    of[7] = fmaxf(acc3.y * inv + b1.w + r1.w, 0.f);

    if (writeFrag) {
        // dims [8i, 8i+8) = hfrag chunk c=i: ks=i>>2, li=(node&15)+((i&3)<<4)
        int tile = node >> 4, r16 = node & 15;
        unsigned short* p0 = fragOut +
            ((size_t)((tile * 4 + (i >> 2)) * 64 + r16 + ((i & 3) << 4)) << 3);
        ushort4 ua, ub;
        ua.x = f2b(of[0]); ua.y = f2b(of[1]); ua.z = f2b(of[2]); ua.w = f2b(of[3]);
        ub.x = f2b(of[4]); ub.y = f2b(of[5]); ub.z = f2b(of[6]); ub.w = f2b(of[7]);
        *(ushort4*)p0 = ua;
        *(ushort4*)(p0 + 4) = ub;
    } else {
        float* po = outF + (size_t)node * DIM + d0;
        *(float4*)po = make_float4(of[0], of[1], of[2], of[3]);
        *(float4*)(po + 4) = make_float4(of[4], of[5], of[6], of[7]);
    }
}

extern "C" void kernel_launch(void* const* d_in, const int* in_sizes, int n_in,
                              void* d_out, int out_size, void* d_ws, size_t ws_size,
                              hipStream_t stream) {
    const float* x    = (const float*)d_in[0];
    const int*   ei   = (const int*)d_in[1];
    const float* Wl   = (const float*)d_in[2];
    const float* bl   = (const float*)d_in[3];
    const float* Wr   = (const float*)d_in[4];
    const float* br   = (const float*)d_in[5];
    const float* att  = (const float*)d_in[6];
    const float* bias = (const float*)d_in[7];
    const float* Wres = (const float*)d_in[8];
    const float* bres = (const float*)d_in[9];

    int n = in_sizes[0] / DIM;
    int E = in_sizes[1] / 2;
    int ntiles = (n + 15) >> 4;
    const int* srcIdx = ei;
    const int* dstIdx = ei + E;

    // workspace layout
    float* resb = (float*)d_ws;
    unsigned short* xlb   = (unsigned short*)(resb + (size_t)n * DIM);
    unsigned short* xrb   = xlb + (size_t)n * DIM;
    unsigned short* hfrag = xrb + (size_t)n * DIM;
    unsigned short* wfrag = hfrag + (size_t)ntiles * 16 * DIM;
    int* rowptr = (int*)(wfrag + 2 * 3 * DIM * DIM);
    int* tmpc   = rowptr + (n + 1);
    int* srt    = tmpc + n;                 // E+n used, +8 pad
    int* bsum   = srt + (E + n + 8);

    int nb1 = (n + 255) / 256;   // 196 <= 256

    k_pre<<<48 + ntiles, 256, 0, stream>>>(Wl, Wr, Wres, wfrag, x, hfrag, n, ntiles);
    hipMemsetAsync(tmpc, 0, (size_t)n * sizeof(int), stream);
    k_count<<<(E + 255) / 256, 256, 0, stream>>>(dstIdx, E, tmpc);
    k_scan1<<<nb1, 256, 0, stream>>>(tmpc, n, rowptr, bsum);
    k_scan2<<<1, 256, 0, stream>>>(bsum, nb1);
    k_scan3<<<nb1, 256, 0, stream>>>(rowptr, bsum, n, tmpc);
    k_scatter<<<(E + n + 255) / 256, 256, 0, stream>>>(srcIdx, dstIdx, E, n, tmpc, srt);

    int gx = (ntiles + 4 * TPW - 1) / (4 * TPW);
    for (int l = 0; l < 2; l++) {
        dim3 g(gx, 3);
        k_gemm<<<g, 256, 0, stream>>>(hfrag, wfrag + (size_t)l * 3 * 4 * 8 * 64 * 8,
                                      bl + (size_t)l * DIM, br + (size_t)l * DIM, bres,
                                      xlb, xrb, resb, ntiles);
        k_aggr<<<(n + 3) / 4, 256, 0, stream>>>(xlb, xrb, resb, att + (size_t)l * DIM,
                                                bias + (size_t)l * DIM, rowptr, srt,
                                                (float*)d_out, hfrag, (l == 0) ? 1 : 0, n);
    }
}

// Round 9
// 216.562 us; speedup vs baseline: 1.0955x; 1.0955x over previous
//
#include <hip/hip_runtime.h>
#include <math.h>

// GATv2 x2 layers, N=50000, E=600000, D=128.
//  CSR over dst (zero+count+scan(fused)+scatter) ->
//  per layer: register-resident-W MFMA GEMM (XL bf16, XR bf16, RES fp32),
//  then per-node aggregation: 1 wave/node, two contiguous 32-lane halves,
//  4 dims/lane uint2 gathers, 4-edge unroll, native-f32x2 math (compiler
//  emits v_pk_*), no-max softmax via exp2 (validated r6-r8), clamp 120.

#define DIM 128
#define NEG_SLOPE 0.2f
#define TPW 4

typedef __attribute__((ext_vector_type(8))) short short8;
typedef __attribute__((ext_vector_type(4))) float floatx4;
typedef __attribute__((ext_vector_type(2))) float f32x2;

static __device__ __forceinline__ unsigned short f2b(float f) {
    unsigned u = __float_as_uint(f);
    unsigned r = (u + 0x7FFFu + ((u >> 16) & 1u)) >> 16;   // RNE
    return (unsigned short)r;
}
// one u32 holding two bf16 (lo = dim d, hi = dim d+1) -> f32 pair
static __device__ __forceinline__ f32x2 cvt2(unsigned u) {
    f32x2 r;
    r.x = __uint_as_float(u << 16);
    r.y = __uint_as_float(u & 0xffff0000u);
    return r;
}
static __device__ __forceinline__ f32x2 abs2(f32x2 a) {
    f32x2 r;
    r.x = __builtin_fabsf(a.x);
    r.y = __builtin_fabsf(a.y);
    return r;
}

// ---------------- CSR build ----------------
__global__ void k_count(const int* __restrict__ dst, int E, int* __restrict__ counts) {
    int k = blockIdx.x * blockDim.x + threadIdx.x;
    if (k < E) atomicAdd(&counts[dst[k]], 1);
}

// inclusive scan of (counts+1) within 256-blocks -> rowptr[i+1], block totals -> bsum
__global__ void k_scan1(const int* __restrict__ counts, int n,
                        int* __restrict__ rowptr, int* __restrict__ bsum) {
    __shared__ int s[256];
    int tid = threadIdx.x;
    int i = blockIdx.x * 256 + tid;
    int v = (i < n) ? (counts[i] + 1) : 0;   // +1 self loop
    s[tid] = v;
    __syncthreads();
    for (int off = 1; off < 256; off <<= 1) {
        int t = (tid >= off) ? s[tid - off] : 0;
        __syncthreads();
        s[tid] += t;
        __syncthreads();
    }
    if (i < n) rowptr[i + 1] = s[tid];
    if (tid == 255) bsum[blockIdx.x] = s[255];
}

// fused: scan bsum in-block (nb<=256), add offsets, emit cursors. 1 dispatch.
__global__ void k_scan3(int* __restrict__ rowptr, const int* __restrict__ bsum,
                        int n, int* __restrict__ counts_to_cursors, int nb) {
    __shared__ int s[256];
    int tid = threadIdx.x;
    int v = (tid < nb) ? bsum[tid] : 0;
    s[tid] = v;
    __syncthreads();
    for (int off = 1; off < 256; off <<= 1) {
        int t = (tid >= off) ? s[tid - off] : 0;
        __syncthreads();
        s[tid] += t;
        __syncthreads();
    }
    int add = (blockIdx.x > 0) ? s[blockIdx.x - 1] : 0;
    int i = blockIdx.x * 256 + tid;
    if (i < n) {
        int cnt = counts_to_cursors[i] + 1;
        int vv = rowptr[i + 1] + add;
        rowptr[i + 1] = vv;
        counts_to_cursors[i] = vv - cnt;  // cursor = exclusive prefix
    }
    if (i == 0) rowptr[0] = 0;
}

__global__ void k_scatter(const int* __restrict__ src, const int* __restrict__ dst,
                          int E, int n, int* __restrict__ cur, int* __restrict__ srt) {
    int k = blockIdx.x * blockDim.x + threadIdx.x;
    int tot = E + n;
    if (k >= tot) return;
    int s, d;
    if (k < E) { s = src[k]; d = dst[k]; }
    else       { s = k - E;  d = s; }
    int p = atomicAdd(&cur[d], 1);
    srt[p] = s;
}

// ---------------- fused pre-pass: W frag + H frag + tmpc zero ----------------
__global__ void k_pre(const float* __restrict__ Wl, const float* __restrict__ Wr,
                      const float* __restrict__ Wres, unsigned short* __restrict__ wfrag,
                      const float* __restrict__ h, unsigned short* __restrict__ hfrag,
                      int* __restrict__ tmpc, int n, int ntiles) {
    int blk = blockIdx.x;
    if (blk < 48) {
        int idx = blk * 256 + threadIdx.x;      // < 2*3*4*8*64 = 12288
        int lane = idx & 63;
        int nr   = (idx >> 6) & 7;
        int ks   = (idx >> 9) & 3;
        int v    = idx >> 11;                   // l*3+sec
        int sec = v % 3, l = v / 3;
        const float* W = (sec == 0) ? (Wl + l * DIM * DIM)
                       : (sec == 1) ? (Wr + l * DIM * DIM) : Wres;
        int nn = nr * 16 + (lane & 15);
        int k0 = ks * 32 + ((lane >> 4) << 3);
        ushort4 a, b;
        a.x = f2b(W[(k0 + 0) * DIM + nn]); a.y = f2b(W[(k0 + 1) * DIM + nn]);
        a.z = f2b(W[(k0 + 2) * DIM + nn]); a.w = f2b(W[(k0 + 3) * DIM + nn]);
        b.x = f2b(W[(k0 + 4) * DIM + nn]); b.y = f2b(W[(k0 + 5) * DIM + nn]);
        b.z = f2b(W[(k0 + 6) * DIM + nn]); b.w = f2b(W[(k0 + 7) * DIM + nn]);
        *(ushort4*)(wfrag + (size_t)idx * 8) = a;
        *(ushort4*)(wfrag + (size_t)idx * 8 + 4) = b;
    } else if (blk < 48 + ntiles) {
        int idx = (blk - 48) * 256 + threadIdx.x;
        int lane = idx & 63;
        int ks   = (idx >> 6) & 3;
        int tile = idx >> 8;
        int row  = tile * 16 + (lane & 15);
        int col0 = ks * 32 + ((lane >> 4) << 3);
        ushort4 a = {0, 0, 0, 0}, b = {0, 0, 0, 0};
        if (row < n) {
            float4 v0 = *(const float4*)(h + (size_t)row * DIM + col0);
            float4 v1 = *(const float4*)(h + (size_t)row * DIM + col0 + 4);
            a.x = f2b(v0.x); a.y = f2b(v0.y); a.z = f2b(v0.z); a.w = f2b(v0.w);
            b.x = f2b(v1.x); b.y = f2b(v1.y); b.z = f2b(v1.z); b.w = f2b(v1.w);
        }
        *(ushort4*)(hfrag + (size_t)idx * 8) = a;
        *(ushort4*)(hfrag + (size_t)idx * 8 + 4) = b;
    } else {
        int i = (blk - 48 - ntiles) * 256 + threadIdx.x;
        if (i < n) tmpc[i] = 0;
    }
}

// ---------------- register-resident-W MFMA GEMM ----------------
__global__ __launch_bounds__(256, 2) void k_gemm(
    const unsigned short* __restrict__ hfrag, const unsigned short* __restrict__ wfrag,
    const float* __restrict__ bl, const float* __restrict__ br, const float* __restrict__ bres,
    unsigned short* __restrict__ XLb, unsigned short* __restrict__ XRb,
    float* __restrict__ RES, int ntiles)
{
    int sec  = blockIdx.y;
    int lane = threadIdx.x & 63;
    int w    = threadIdx.x >> 6;

    const unsigned short* wbase = wfrag + (size_t)sec * (4 * 8 * 64 * 8);
    short8 bf[4][8];
#pragma unroll
    for (int ks = 0; ks < 4; ks++)
#pragma unroll
        for (int nr = 0; nr < 8; nr++)
            bf[ks][nr] = *(const short8*)(wbase + (((ks * 8 + nr) * 64 + lane) << 3));

    const float* bias = (sec == 0) ? bl : (sec == 1) ? br : bres;
    int colb = (lane >> 4) << 2;
    float4 bv[8];
#pragma unroll
    for (int nr = 0; nr < 8; nr++) bv[nr] = *(const float4*)(bias + nr * 16 + colb);

    int wid = blockIdx.x * 4 + w;
#pragma unroll
    for (int i = 0; i < TPW; i++) {
        int t = wid * TPW + i;
        if (t >= ntiles) break;
        short8 a[4];
#pragma unroll
        for (int ks = 0; ks < 4; ks++)
            a[ks] = *(const short8*)(hfrag + (((t * 4 + ks) * 64 + lane) << 3));
        floatx4 acc[8];
#pragma unroll
        for (int nr = 0; nr < 8; nr++) acc[nr] = (floatx4){0.f, 0.f, 0.f, 0.f};
#pragma unroll
        for (int ks = 0; ks < 4; ks++)
#pragma unroll
            for (int nr = 0; nr < 8; nr++)
                acc[nr] = __builtin_amdgcn_mfma_f32_16x16x32_bf16(bf[ks][nr], a[ks], acc[nr], 0, 0, 0);

        int row = t * 16 + (lane & 15);
        size_t rb = (size_t)row * DIM;
#pragma unroll
        for (int nr = 0; nr < 8; nr++) {
            float4 o;
            o.x = acc[nr][0] + bv[nr].x;
            o.y = acc[nr][1] + bv[nr].y;
            o.z = acc[nr][2] + bv[nr].z;
            o.w = acc[nr][3] + bv[nr].w;
            int col = nr * 16 + colb;
            if (sec == 2) {
                *(float4*)(RES + rb + col) = o;
            } else {
                ushort4 u;
                u.x = f2b(o.x); u.y = f2b(o.y); u.z = f2b(o.z); u.w = f2b(o.w);
                if (sec == 0) *(ushort4*)(XLb + rb + col) = u;
                else          *(ushort4*)(XRb + rb + col) = u;
            }
        }
    }
}

// ---------------- aggregation ----------------
// 1 wave/node, two contiguous 32-lane halves, 4 dims/lane (uint2), 4-edge
// unroll, native f32x2 math, no-max softmax via exp2 (att has log2e folded).
#define EDGE_P(K)                                                        \
    f32x2 v01_##K = cvt2(e##K.x), v23_##K = cvt2(e##K.y);                \
    float p##K;                                                          \
    {                                                                    \
        f32x2 t01 = v01_##K + x01;                                       \
        f32x2 t23 = v23_##K + x23;                                       \
        f32x2 pp = a6_01 * t01 + a4_01 * abs2(t01);                      \
        pp += a6_23 * t23;                                               \
        pp += a4_23 * abs2(t23);                                         \
        p##K = pp.x + pp.y;                                              \
    }

__global__ __launch_bounds__(256, 8) void k_aggr(
    const unsigned short* __restrict__ XLb, const unsigned short* __restrict__ XRb,
    const float* __restrict__ RES, const float* __restrict__ att,
    const float* __restrict__ bias, const int* __restrict__ rowptr,
    const int* __restrict__ srt, float* __restrict__ outF,
    unsigned short* __restrict__ fragOut, int writeFrag, int n)
{
    int wave = threadIdx.x >> 6;
    int lane = threadIdx.x & 63;
    int node = blockIdx.x * 4 + wave;
    if (node >= n) return;
    int half = lane >> 5, sl = lane & 31;
    int d0 = sl << 2;

    const float S6 = 0.6f * 1.44269504089f;   // log2(e) folded
    const float S4 = 0.4f * 1.44269504089f;
    float4 af = *(const float4*)(att + d0);
    f32x2 a6_01 = {S6 * af.x, S6 * af.y}, a6_23 = {S6 * af.z, S6 * af.w};
    f32x2 a4_01 = {S4 * af.x, S4 * af.y}, a4_23 = {S4 * af.z, S4 * af.w};

    uint2 xru = *(const uint2*)(XRb + (size_t)node * DIM + d0);
    f32x2 x01 = cvt2(xru.x), x23 = cvt2(xru.y);

    int beg = rowptr[node], end = rowptr[node + 1];
    int len = end - beg;
    int hl = (len + 1) >> 1;
    int sb = beg + half * hl;
    int se = half ? end : (beg + hl);

    const uint2* R = (const uint2*)XLb;   // row i slice at R[i*32 + sl]

    f32x2 acc01 = {0.f, 0.f}, acc23 = {0.f, 0.f};
    float den = 0.f;

    for (int j = sb; j < se; j += 4) {
        int j1 = (j + 1 < se) ? j + 1 : j;
        int j2 = (j + 2 < se) ? j + 2 : j;
        int j3 = (j + 3 < se) ? j + 3 : j;
        int s0 = srt[j], s1 = srt[j1], s2 = srt[j2], s3 = srt[j3];
        uint2 e0 = R[(size_t)s0 * 32 + sl];
        uint2 e1 = R[(size_t)s1 * 32 + sl];
        uint2 e2 = R[(size_t)s2 * 32 + sl];
        uint2 e3 = R[(size_t)s3 * 32 + sl];
        EDGE_P(0) EDGE_P(1) EDGE_P(2) EDGE_P(3)
#pragma unroll
        for (int off = 16; off >= 1; off >>= 1) {
            p0 += __shfl_xor(p0, off);
            p1 += __shfl_xor(p1, off);
            p2 += __shfl_xor(p2, off);
            p3 += __shfl_xor(p3, off);
        }
        float w0 = __builtin_exp2f(fminf(p0, 120.f));
        float w1 = (j + 1 < se) ? __builtin_exp2f(fminf(p1, 120.f)) : 0.f;
        float w2 = (j + 2 < se) ? __builtin_exp2f(fminf(p2, 120.f)) : 0.f;
        float w3 = (j + 3 < se) ? __builtin_exp2f(fminf(p3, 120.f)) : 0.f;
        den += (w0 + w1) + (w2 + w3);
        acc01 += w0 * v01_0 + w1 * v01_1;
        acc23 += w0 * v23_0 + w1 * v23_1;
        acc01 += w2 * v01_2 + w3 * v01_3;
        acc23 += w2 * v23_2 + w3 * v23_3;
    }

    // merge the two halves (pure sums)
    den     += __shfl_xor(den, 32);
    acc01.x += __shfl_xor(acc01.x, 32);
    acc01.y += __shfl_xor(acc01.y, 32);
    acc23.x += __shfl_xor(acc23.x, 32);
    acc23.y += __shfl_xor(acc23.y, 32);
    if (half) return;

    float inv = 1.f / (den + 1e-16f);
    float4 r4 = *(const float4*)(RES + (size_t)node * DIM + d0);
    float4 b4 = *(const float4*)(bias + d0);
    float4 o;
    o.x = fmaxf(acc01.x * inv + b4.x + r4.x, 0.f);
    o.y = fmaxf(acc01.y * inv + b4.y + r4.y, 0.f);
    o.z = fmaxf(acc23.x * inv + b4.z + r4.z, 0.f);
    o.w = fmaxf(acc23.y * inv + b4.w + r4.w, 0.f);

    if (writeFrag) {
        int tile = node >> 4;
        int ks = sl >> 3;
        int li = (node & 15) + (((sl >> 1) & 3) << 4);
        int j0 = (sl & 1) << 2;
        ushort4 u;
        u.x = f2b(o.x); u.y = f2b(o.y); u.z = f2b(o.z); u.w = f2b(o.w);
        *(ushort4*)(fragOut + ((size_t)((tile * 4 + ks) * 64 + li) << 3) + j0) = u;
    } else {
        *(float4*)(outF + (size_t)node * DIM + d0) = o;
    }
}

extern "C" void kernel_launch(void* const* d_in, const int* in_sizes, int n_in,
                              void* d_out, int out_size, void* d_ws, size_t ws_size,
                              hipStream_t stream) {
    const float* x    = (const float*)d_in[0];
    const int*   ei   = (const int*)d_in[1];
    const float* Wl   = (const float*)d_in[2];
    const float* bl   = (const float*)d_in[3];
    const float* Wr   = (const float*)d_in[4];
    const float* br   = (const float*)d_in[5];
    const float* att  = (const float*)d_in[6];
    const float* bias = (const float*)d_in[7];
    const float* Wres = (const float*)d_in[8];
    const float* bres = (const float*)d_in[9];

    int n = in_sizes[0] / DIM;
    int E = in_sizes[1] / 2;
    int ntiles = (n + 15) >> 4;
    const int* srcIdx = ei;
    const int* dstIdx = ei + E;

    // workspace layout
    float* resb = (float*)d_ws;
    unsigned short* xlb   = (unsigned short*)(resb + (size_t)n * DIM);
    unsigned short* xrb   = xlb + (size_t)n * DIM;
    unsigned short* hfrag = xrb + (size_t)n * DIM;
    unsigned short* wfrag = hfrag + (size_t)ntiles * 16 * DIM;
    int* rowptr = (int*)(wfrag + 2 * 3 * DIM * DIM);
    int* tmpc   = rowptr + (n + 1);
    int* srt    = tmpc + n;                 // E+n used, +8 pad
    int* bsum   = srt + (E + n + 8);

    int nb1 = (n + 255) / 256;   // 196 <= 256

    k_pre<<<48 + ntiles + nb1, 256, 0, stream>>>(Wl, Wr, Wres, wfrag, x, hfrag,
                                                 tmpc, n, ntiles);
    k_count<<<(E + 255) / 256, 256, 0, stream>>>(dstIdx, E, tmpc);
    k_scan1<<<nb1, 256, 0, stream>>>(tmpc, n, rowptr, bsum);
    k_scan3<<<nb1, 256, 0, stream>>>(rowptr, bsum, n, tmpc, nb1);
    k_scatter<<<(E + n + 255) / 256, 256, 0, stream>>>(srcIdx, dstIdx, E, n, tmpc, srt);

    int gx = (ntiles + 4 * TPW - 1) / (4 * TPW);
    for (int l = 0; l < 2; l++) {
        dim3 g(gx, 3);
        k_gemm<<<g, 256, 0, stream>>>(hfrag, wfrag + (size_t)l * 3 * 4 * 8 * 64 * 8,
                                      bl + (size_t)l * DIM, br + (size_t)l * DIM, bres,
                                      xlb, xrb, resb, ntiles);
        k_aggr<<<(n + 3) / 4, 256, 0, stream>>>(xlb, xrb, resb, att + (size_t)l * DIM,
                                                bias + (size_t)l * DIM, rowptr, srt,
                                                (float*)d_out, hfrag, (l == 0) ? 1 : 0, n);
    }
}